// Round 3
// baseline (116.621 us; speedup 1.0000x reference)
//
#include <hip/hip_runtime.h>
#include <hip/hip_bf16.h>
#include <stdint.h>

// BatchHardTripletLoss: N=4096, D=512, C=128, margin=0.3
// dist monotone-decreasing in gram => hardest-pos = min gram (same label, j!=i),
// hardest-neg = max gram (diff label). Gram symmetric => upper-triangular tiles
// only (528); off-diag tiles feed row- and col-direction reductions.
// R3: double-buffered LDS (1 barrier/K-iter, prefetch dist 1) — gram was
// latency/barrier-bound at 2.06 blocks/CU. Final reduction fused into gram
// via completion counter (last block finalizes with coherent atomic reads).

#define NROW 4096
#define DIM  512
#define MARGIN 0.3f
#define BT 128
#define BK 32
#define KITERS (DIM / BK)                 // 16
#define NTILE (NROW / BT)                 // 32
#define NPAIR (NTILE * (NTILE + 1) / 2)   // 528
#define POS_INIT 0xFFFFFFFFu
#define NEG_INIT 0u

typedef __attribute__((ext_vector_type(8))) __bf16 bf16x8;
typedef __attribute__((ext_vector_type(4))) float  f32x4;

// monotone float<->uint: order-preserving for atomicMin/Max on unsigned.
// enc(finite f) can never equal POS_INIT (needs NaN) nor NEG_INIT (needs -NaN),
// so the init sentinels double as "no positive/negative seen" flags.
__device__ __forceinline__ unsigned enc(float f) {
    unsigned u = __float_as_uint(f);
    return (u & 0x80000000u) ? ~u : (u | 0x80000000u);
}
__device__ __forceinline__ float dec(unsigned e) {
    return (e & 0x80000000u) ? __uint_as_float(e & 0x7fffffffu)
                             : __uint_as_float(~e);
}

__device__ __forceinline__ unsigned short f2bf(float f) {
    __hip_bfloat16 h = __float2bfloat16(f);
    return *reinterpret_cast<unsigned short*>(&h);
}

__device__ __forceinline__ void async_copy16(const void* g, void* l) {
    __builtin_amdgcn_global_load_lds(
        (const __attribute__((address_space(1))) unsigned int*)g,
        (__attribute__((address_space(3))) unsigned int*)l,
        16, 0, 0);
}

// ---- kernel 1: L2-normalize rows -> bf16, + init reduction arrays/counter ----
// one wave per row; 4 waves/block; 1024 blocks (first 16 also init pos/neg)
__global__ void tl_norm(const float* __restrict__ E,
                        __hip_bfloat16* __restrict__ Ebf,
                        unsigned* __restrict__ posArr,
                        unsigned* __restrict__ negArr,
                        unsigned* __restrict__ doneCnt) {
    if (blockIdx.x < 16) {
        int t = blockIdx.x * 256 + threadIdx.x;   // covers 4096
        posArr[t] = POS_INIT;
        negArr[t] = NEG_INIT;
        if (t == 0) *doneCnt = 0;
    }
    int wave = threadIdx.x >> 6;
    int lane = threadIdx.x & 63;
    int row  = blockIdx.x * 4 + wave;

    const float4* src = (const float4*)(E + (size_t)row * DIM); // 128 float4/row
    float4 v0 = src[lane];
    float4 v1 = src[lane + 64];
    float ss = v0.x*v0.x + v0.y*v0.y + v0.z*v0.z + v0.w*v0.w
             + v1.x*v1.x + v1.y*v1.y + v1.z*v1.z + v1.w*v1.w;
    #pragma unroll
    for (int m = 32; m >= 1; m >>= 1) ss += __shfl_xor(ss, m);
    float inv = 1.0f / fmaxf(sqrtf(ss), 1e-12f);

    ushort4 o0, o1;
    o0.x = f2bf(v0.x * inv); o0.y = f2bf(v0.y * inv);
    o0.z = f2bf(v0.z * inv); o0.w = f2bf(v0.w * inv);
    o1.x = f2bf(v1.x * inv); o1.y = f2bf(v1.y * inv);
    o1.z = f2bf(v1.z * inv); o1.w = f2bf(v1.w * inv);
    ushort4* dst = (ushort4*)(Ebf + (size_t)row * DIM);
    dst[lane]      = o0;
    dst[lane + 64] = o1;
}

// ---- kernel 2: upper-triangular tiled bf16 MFMA Gram, fused min/max,
//      double-buffered LDS, last-block final reduction ----
__global__ void tl_gram(const __hip_bfloat16* __restrict__ Ebf,
                        const int* __restrict__ labels,
                        unsigned* __restrict__ posArr,
                        unsigned* __restrict__ negArr,
                        unsigned* __restrict__ doneCnt,
                        float* __restrict__ out) {
    __shared__ __align__(16) __hip_bfloat16 At[2][BT * BK]; // 2 x 8 KB
    __shared__ __align__(16) __hip_bfloat16 Bt[2][BT * BK]; // 2 x 8 KB
    __shared__ int rowLab[BT];
    __shared__ int colLab[BT];
    __shared__ int lastFlag;
    __shared__ float ssum[4];
    __shared__ int   scnt[4];

    // triangular decode: blockIdx.x -> (bi, bj) with bi <= bj
    int t = blockIdx.x, bi = 0, rowlen = NTILE;
    while (t >= rowlen) { t -= rowlen; rowlen--; bi++; }
    const int bj = bi + t;

    const int tid  = threadIdx.x;
    const int wave = tid >> 6;
    const int lane = tid & 63;
    const int quad = lane >> 4;
    const int l16  = lane & 15;
    const int wr   = wave >> 1;   // wave row (0..1): rows wr*64..+63
    const int wc   = wave & 1;    // wave col (0..1): cols wc*64..+63
    const int tileI = bi * BT;
    const int tileJ = bj * BT;
    const bool diag = (bi == bj);

    if (tid < BT) rowLab[tid] = labels[tileI + tid];
    else          colLab[tid - BT] = labels[tileJ + (tid - BT)];

    // staging: chunk c = wave*2+t covers LDS rows [c*16, c*16+16);
    // lane l -> base + l*16 B -> row c*16 + l/4, k = (l&3)*8 (wave-uniform base)
    const int sRow = wave * 32 + (lane >> 2);
    const int sK   = (lane & 3) * 8;
    const __hip_bfloat16* gA = Ebf + (size_t)(tileI + sRow) * DIM + sK;
    const __hip_bfloat16* gB = Ebf + (size_t)(tileJ + sRow) * DIM + sK;
    const int ldsOff0 = (wave * 2 + 0) * 512;
    const int ldsOff1 = (wave * 2 + 1) * 512;

    f32x4 acc[4][4] = {};

    // prologue: stage iter 0 into buffer 0
    async_copy16(gA,            &At[0][ldsOff0]);
    async_copy16(gA + 16 * DIM, &At[0][ldsOff1]);
    async_copy16(gB,            &Bt[0][ldsOff0]);
    async_copy16(gB + 16 * DIM, &Bt[0][ldsOff1]);

    for (int it = 0; it < KITERS; it++) {
        // barrier drains copies for iter `it` (in flight during prev MFMA stage)
        // and guarantees all waves finished ds_reads of the buffer we overwrite.
        __syncthreads();

        if (it + 1 < KITERS) {
            const int k1 = (it + 1) * BK;
            const int nb = (it + 1) & 1;
            async_copy16(gA + k1,            &At[nb][ldsOff0]);
            async_copy16(gA + k1 + 16 * DIM, &At[nb][ldsOff1]);
            async_copy16(gB + k1,            &Bt[nb][ldsOff0]);
            async_copy16(gB + k1 + 16 * DIM, &Bt[nb][ldsOff1]);
        }

        const int cb = it & 1;
        bf16x8 a[4], b[4];
        #pragma unroll
        for (int mi = 0; mi < 4; mi++)
            a[mi] = *(const bf16x8*)&At[cb][(wr * 64 + mi * 16 + l16) * BK + quad * 8];
        #pragma unroll
        for (int ni = 0; ni < 4; ni++)
            b[ni] = *(const bf16x8*)&Bt[cb][(wc * 64 + ni * 16 + l16) * BK + quad * 8];

        #pragma unroll
        for (int mi = 0; mi < 4; mi++)
            #pragma unroll
            for (int ni = 0; ni < 4; ni++)
                acc[mi][ni] = __builtin_amdgcn_mfma_f32_16x16x32_bf16(
                    a[mi], b[ni], acc[mi][ni], 0, 0, 0);
    }

    // C/D layout: col = wc*64+ni*16+l16 (lane), row = wr*64+mi*16+quad*4+reg
    int rl[16], cl[4], clocv[4];
    #pragma unroll
    for (int mi = 0; mi < 4; mi++)
        #pragma unroll
        for (int reg = 0; reg < 4; reg++)
            rl[mi * 4 + reg] = rowLab[wr * 64 + mi * 16 + quad * 4 + reg];
    #pragma unroll
    for (int ni = 0; ni < 4; ni++) {
        clocv[ni] = wc * 64 + ni * 16 + l16;
        cl[ni] = colLab[clocv[ni]];
    }

    // ---- row pass: reduce over this tile's columns, for rows of tileI ----
    #pragma unroll
    for (int mi = 0; mi < 4; mi++) {
        #pragma unroll
        for (int reg = 0; reg < 4; reg++) {
            const int rloc = wr * 64 + mi * 16 + quad * 4 + reg;
            const int lr   = rl[mi * 4 + reg];
            const int gi   = tileI + rloc;
            float pmin =  INFINITY;
            float nmax = -INFINITY;
            #pragma unroll
            for (int ni = 0; ni < 4; ni++) {
                const int gj  = tileJ + clocv[ni];
                const float g = acc[mi][ni][reg];
                const bool same = (lr == cl[ni]);
                if (same && gi != gj) pmin = fminf(pmin, g);
                if (!same)            nmax = fmaxf(nmax, g);
            }
            #pragma unroll
            for (int m = 1; m < 16; m <<= 1) {
                pmin = fminf(pmin, __shfl_xor(pmin, m));
                nmax = fmaxf(nmax, __shfl_xor(nmax, m));
            }
            if (l16 == 0) {
                if (pmin <  INFINITY) atomicMin(&posArr[gi], enc(pmin));
                if (nmax > -INFINITY) atomicMax(&negArr[gi], enc(nmax));
            }
        }
    }

    // ---- col pass (off-diag only): reduce over rows, for rows of tileJ ----
    if (!diag) {
        #pragma unroll
        for (int ni = 0; ni < 4; ni++) {
            const int lc = cl[ni];
            const int gj = tileJ + clocv[ni];
            float pmin =  INFINITY;
            float nmax = -INFINITY;
            #pragma unroll
            for (int mi = 0; mi < 4; mi++) {
                #pragma unroll
                for (int reg = 0; reg < 4; reg++) {
                    const float g = acc[mi][ni][reg];
                    const bool same = (rl[mi * 4 + reg] == lc);
                    if (same) pmin = fminf(pmin, g);
                    else      nmax = fmaxf(nmax, g);
                }
            }
            pmin = fminf(pmin, __shfl_xor(pmin, 16));
            pmin = fminf(pmin, __shfl_xor(pmin, 32));
            nmax = fmaxf(nmax, __shfl_xor(nmax, 16));
            nmax = fmaxf(nmax, __shfl_xor(nmax, 32));
            if (quad == 0) {
                if (pmin <  INFINITY) atomicMin(&posArr[gj], enc(pmin));
                if (nmax > -INFINITY) atomicMax(&negArr[gj], enc(nmax));
            }
        }
    }

    // ---- completion: last block computes the final mean ----
    __threadfence();                       // release: our atomics visible
    if (tid == 0) {
        unsigned prev = atomicAdd(doneCnt, 1u);
        lastFlag = (prev == NPAIR - 1) ? 1 : 0;
    }
    __syncthreads();
    if (lastFlag) {
        __threadfence();                   // acquire side
        float sum = 0.0f;
        int   count = 0;
        for (int i = tid; i < NROW; i += 256) {
            const unsigned pe = atomicOr(&posArr[i], 0u);  // coherent read
            const unsigned ne = atomicOr(&negArr[i], 0u);
            const bool valid = (pe != POS_INIT) && (ne != NEG_INIT);
            const float dap = sqrtf(fmaxf(2.0f - 2.0f * dec(pe), 0.0f));
            const float dan = sqrtf(fmaxf(2.0f - 2.0f * dec(ne), 0.0f));
            const float per = fmaxf(dap - dan + MARGIN, 0.0f);
            if (valid) { sum += per; count += 1; }
        }
        #pragma unroll
        for (int m = 32; m >= 1; m >>= 1) {
            sum   += __shfl_xor(sum, m);
            count += __shfl_xor(count, m);
        }
        if (lane == 0) { ssum[wave] = sum; scnt[wave] = count; }
        __syncthreads();
        if (tid == 0) {
            float s = ssum[0] + ssum[1] + ssum[2] + ssum[3];
            int   c = scnt[0] + scnt[1] + scnt[2] + scnt[3];
            out[0] = (c > 0) ? (s / (float)c) : 0.0f;
        }
    }
}

extern "C" void kernel_launch(void* const* d_in, const int* in_sizes, int n_in,
                              void* d_out, int out_size, void* d_ws, size_t ws_size,
                              hipStream_t stream) {
    const float* E      = (const float*)d_in[0];
    const int*   labels = (const int*)d_in[1];
    float*       out    = (float*)d_out;

    char* ws = (char*)d_ws;
    __hip_bfloat16* Ebf   = (__hip_bfloat16*)ws;                       // 4 MB
    unsigned* posArr      = (unsigned*)(ws + (size_t)NROW * DIM * 2);  // 16 KB
    unsigned* negArr      = posArr + NROW;                             // 16 KB
    unsigned* doneCnt     = negArr + NROW;                             // 4 B

    tl_norm<<<NROW / 4, 256, 0, stream>>>(E, Ebf, posArr, negArr, doneCnt);
    tl_gram<<<NPAIR, 256, 0, stream>>>(Ebf, labels, posArr, negArr, doneCnt, out);
}

// Round 4
// 104.804 us; speedup vs baseline: 1.1127x; 1.1127x over previous
//
#include <hip/hip_runtime.h>
#include <hip/hip_bf16.h>
#include <stdint.h>

// BatchHardTripletLoss: N=4096, D=512, C=128, margin=0.3
// dist monotone-decreasing in gram => hardest-pos = min gram (same label, j!=i),
// hardest-neg = max gram (diff label). Gram symmetric => upper-triangular tiles
// only; off-diag tiles feed row- and col-direction reductions.
// R4: revert R3's dbuf+threadfence-fusion (regressed 3x: compiler emits
// vmcnt(0) before ds_reads due to LDS aliasing, defeating prefetch).
// Change: BT 128->64. Grid 528->2080 blocks => ~8 blocks/CU instead of 2
// (R2 was grid-limited; copy latency unhidden). Same total MFMA + staging.

#define NROW 4096
#define DIM  512
#define MARGIN 0.3f
#define BT 64
#define BK 32
#define NTILE (NROW / BT)                 // 64
#define NPAIR (NTILE * (NTILE + 1) / 2)   // 2080
#define POS_INIT 0xFFFFFFFFu
#define NEG_INIT 0u

typedef __attribute__((ext_vector_type(8))) __bf16 bf16x8;
typedef __attribute__((ext_vector_type(4))) float  f32x4;

// monotone float<->uint: order-preserving for atomicMin/Max on unsigned.
// enc(finite f) never equals POS_INIT (needs NaN) nor NEG_INIT (needs -NaN),
// so init sentinels double as "no positive/negative seen" flags.
__device__ __forceinline__ unsigned enc(float f) {
    unsigned u = __float_as_uint(f);
    return (u & 0x80000000u) ? ~u : (u | 0x80000000u);
}
__device__ __forceinline__ float dec(unsigned e) {
    return (e & 0x80000000u) ? __uint_as_float(e & 0x7fffffffu)
                             : __uint_as_float(~e);
}

__device__ __forceinline__ unsigned short f2bf(float f) {
    __hip_bfloat16 h = __float2bfloat16(f);
    return *reinterpret_cast<unsigned short*>(&h);
}

__device__ __forceinline__ void async_copy16(const void* g, void* l) {
    __builtin_amdgcn_global_load_lds(
        (const __attribute__((address_space(1))) unsigned int*)g,
        (__attribute__((address_space(3))) unsigned int*)l,
        16, 0, 0);
}

// ---- kernel 1: L2-normalize rows -> bf16, + init reduction arrays ----
// one wave per row; 4 waves/block; 1024 blocks (first 16 also init pos/neg)
__global__ void tl_norm(const float* __restrict__ E,
                        __hip_bfloat16* __restrict__ Ebf,
                        unsigned* __restrict__ posArr,
                        unsigned* __restrict__ negArr) {
    if (blockIdx.x < 16) {
        int t = blockIdx.x * 256 + threadIdx.x;   // covers 4096
        posArr[t] = POS_INIT;
        negArr[t] = NEG_INIT;
    }
    int wave = threadIdx.x >> 6;
    int lane = threadIdx.x & 63;
    int row  = blockIdx.x * 4 + wave;

    const float4* src = (const float4*)(E + (size_t)row * DIM); // 128 float4/row
    float4 v0 = src[lane];
    float4 v1 = src[lane + 64];
    float ss = v0.x*v0.x + v0.y*v0.y + v0.z*v0.z + v0.w*v0.w
             + v1.x*v1.x + v1.y*v1.y + v1.z*v1.z + v1.w*v1.w;
    #pragma unroll
    for (int m = 32; m >= 1; m >>= 1) ss += __shfl_xor(ss, m);
    float inv = 1.0f / fmaxf(sqrtf(ss), 1e-12f);

    ushort4 o0, o1;
    o0.x = f2bf(v0.x * inv); o0.y = f2bf(v0.y * inv);
    o0.z = f2bf(v0.z * inv); o0.w = f2bf(v0.w * inv);
    o1.x = f2bf(v1.x * inv); o1.y = f2bf(v1.y * inv);
    o1.z = f2bf(v1.z * inv); o1.w = f2bf(v1.w * inv);
    ushort4* dst = (ushort4*)(Ebf + (size_t)row * DIM);
    dst[lane]      = o0;
    dst[lane + 64] = o1;
}

// ---- kernel 2: upper-triangular 64x64 bf16 MFMA Gram tiles, fused min/max ----
// 4 waves in 2x2; each wave 32x32 via 2x2 of 16x16x32 MFMA. Single-buffered
// LDS, two barriers per K-iter (the proven R2 structure).
__global__ void tl_gram(const __hip_bfloat16* __restrict__ Ebf,
                        const int* __restrict__ labels,
                        unsigned* __restrict__ posArr,
                        unsigned* __restrict__ negArr) {
    __shared__ __align__(16) __hip_bfloat16 At[BT * BK]; // [row][k], 4 KB
    __shared__ __align__(16) __hip_bfloat16 Bt[BT * BK]; // [col][k], 4 KB
    __shared__ int rowLab[BT];
    __shared__ int colLab[BT];

    // triangular decode: blockIdx.x -> (bi, bj) with bi <= bj
    int t = blockIdx.x, bi = 0, rowlen = NTILE;
    while (t >= rowlen) { t -= rowlen; rowlen--; bi++; }
    const int bj = bi + t;

    const int tid  = threadIdx.x;
    const int wave = tid >> 6;
    const int lane = tid & 63;
    const int quad = lane >> 4;
    const int l16  = lane & 15;
    const int wr   = wave >> 1;   // wave row (0..1): rows wr*32..+31
    const int wc   = wave & 1;    // wave col (0..1): cols wc*32..+31
    const int tileI = bi * BT;
    const int tileJ = bj * BT;
    const bool diag = (bi == bj);

    if (tid < BT)            rowLab[tid] = labels[tileI + tid];
    else if (tid < 2 * BT)   colLab[tid - BT] = labels[tileJ + (tid - BT)];

    // staging: wave w stages chunk w (rows w*16..+15) of At AND of Bt.
    // lane l -> base + l*16 B -> row w*16 + l/4, k = (l&3)*8 (wave-uniform base)
    const int sRow = wave * 16 + (lane >> 2);
    const int sK   = (lane & 3) * 8;
    const __hip_bfloat16* gA = Ebf + (size_t)(tileI + sRow) * DIM + sK;
    const __hip_bfloat16* gB = Ebf + (size_t)(tileJ + sRow) * DIM + sK;
    __hip_bfloat16* lA = &At[wave * 512];
    __hip_bfloat16* lB = &Bt[wave * 512];

    f32x4 acc[2][2] = {};

    for (int k0 = 0; k0 < DIM; k0 += BK) {
        async_copy16(gA + k0, lA);
        async_copy16(gB + k0, lB);
        __syncthreads();   // drains this wave's copies; all chunks landed

        bf16x8 a[2], b[2];
        #pragma unroll
        for (int mi = 0; mi < 2; mi++)
            a[mi] = *(const bf16x8*)&At[(wr * 32 + mi * 16 + l16) * BK + quad * 8];
        #pragma unroll
        for (int ni = 0; ni < 2; ni++)
            b[ni] = *(const bf16x8*)&Bt[(wc * 32 + ni * 16 + l16) * BK + quad * 8];

        #pragma unroll
        for (int mi = 0; mi < 2; mi++)
            #pragma unroll
            for (int ni = 0; ni < 2; ni++)
                acc[mi][ni] = __builtin_amdgcn_mfma_f32_16x16x32_bf16(
                    a[mi], b[ni], acc[mi][ni], 0, 0, 0);

        __syncthreads();   // protect next staging overwrite
    }

    // C/D layout: col = wc*32+ni*16+l16 (lane), row = wr*32+mi*16+quad*4+reg
    int rl[8], cl[2], clocv[2];
    #pragma unroll
    for (int mi = 0; mi < 2; mi++)
        #pragma unroll
        for (int reg = 0; reg < 4; reg++)
            rl[mi * 4 + reg] = rowLab[wr * 32 + mi * 16 + quad * 4 + reg];
    #pragma unroll
    for (int ni = 0; ni < 2; ni++) {
        clocv[ni] = wc * 32 + ni * 16 + l16;
        cl[ni] = colLab[clocv[ni]];
    }

    // ---- row pass: reduce over this tile's columns, for rows of tileI ----
    #pragma unroll
    for (int mi = 0; mi < 2; mi++) {
        #pragma unroll
        for (int reg = 0; reg < 4; reg++) {
            const int rloc = wr * 32 + mi * 16 + quad * 4 + reg;
            const int lr   = rl[mi * 4 + reg];
            const int gi   = tileI + rloc;
            float pmin =  INFINITY;
            float nmax = -INFINITY;
            #pragma unroll
            for (int ni = 0; ni < 2; ni++) {
                const int gj  = tileJ + clocv[ni];
                const float g = acc[mi][ni][reg];
                const bool same = (lr == cl[ni]);
                if (same && gi != gj) pmin = fminf(pmin, g);
                if (!same)            nmax = fmaxf(nmax, g);
            }
            #pragma unroll
            for (int m = 1; m < 16; m <<= 1) {
                pmin = fminf(pmin, __shfl_xor(pmin, m));
                nmax = fmaxf(nmax, __shfl_xor(nmax, m));
            }
            if (l16 == 0) {
                if (pmin <  INFINITY) atomicMin(&posArr[gi], enc(pmin));
                if (nmax > -INFINITY) atomicMax(&negArr[gi], enc(nmax));
            }
        }
    }

    // ---- col pass (off-diag only): reduce over rows, for rows of tileJ ----
    if (!diag) {
        #pragma unroll
        for (int ni = 0; ni < 2; ni++) {
            const int lc = cl[ni];
            const int gj = tileJ + clocv[ni];
            float pmin =  INFINITY;
            float nmax = -INFINITY;
            #pragma unroll
            for (int mi = 0; mi < 2; mi++) {
                #pragma unroll
                for (int reg = 0; reg < 4; reg++) {
                    const float g = acc[mi][ni][reg];
                    const bool same = (rl[mi * 4 + reg] == lc);
                    if (same) pmin = fminf(pmin, g);
                    else      nmax = fmaxf(nmax, g);
                }
            }
            pmin = fminf(pmin, __shfl_xor(pmin, 16));
            pmin = fminf(pmin, __shfl_xor(pmin, 32));
            nmax = fmaxf(nmax, __shfl_xor(nmax, 16));
            nmax = fmaxf(nmax, __shfl_xor(nmax, 32));
            if (quad == 0) {
                if (pmin <  INFINITY) atomicMin(&posArr[gj], enc(pmin));
                if (nmax > -INFINITY) atomicMax(&negArr[gj], enc(nmax));
            }
        }
    }
}

// ---- kernel 3: per-row loss + mean over valid rows ----
__global__ void tl_final(const unsigned* __restrict__ posArr,
                         const unsigned* __restrict__ negArr,
                         float* __restrict__ out) {
    const int tid = threadIdx.x; // 256 threads
    float sum = 0.0f;
    int   count = 0;
    for (int i = tid; i < NROW; i += 256) {
        const unsigned pe = posArr[i];
        const unsigned ne = negArr[i];
        const bool valid = (pe != POS_INIT) && (ne != NEG_INIT);
        const float dap = sqrtf(fmaxf(2.0f - 2.0f * dec(pe), 0.0f));
        const float dan = sqrtf(fmaxf(2.0f - 2.0f * dec(ne), 0.0f));
        const float per = fmaxf(dap - dan + MARGIN, 0.0f);
        if (valid) { sum += per; count += 1; }
    }
    #pragma unroll
    for (int m = 32; m >= 1; m >>= 1) {
        sum   += __shfl_xor(sum, m);
        count += __shfl_xor(count, m);
    }
    __shared__ float ssum[4];
    __shared__ int   scnt[4];
    const int wave = tid >> 6, lane = tid & 63;
    if (lane == 0) { ssum[wave] = sum; scnt[wave] = count; }
    __syncthreads();
    if (tid == 0) {
        float s = ssum[0] + ssum[1] + ssum[2] + ssum[3];
        int   c = scnt[0] + scnt[1] + scnt[2] + scnt[3];
        out[0] = (c > 0) ? (s / (float)c) : 0.0f;
    }
}

extern "C" void kernel_launch(void* const* d_in, const int* in_sizes, int n_in,
                              void* d_out, int out_size, void* d_ws, size_t ws_size,
                              hipStream_t stream) {
    const float* E      = (const float*)d_in[0];
    const int*   labels = (const int*)d_in[1];
    float*       out    = (float*)d_out;

    char* ws = (char*)d_ws;
    __hip_bfloat16* Ebf   = (__hip_bfloat16*)ws;                       // 4 MB
    unsigned* posArr      = (unsigned*)(ws + (size_t)NROW * DIM * 2);  // 16 KB
    unsigned* negArr      = posArr + NROW;                             // 16 KB

    tl_norm<<<NROW / 4, 256, 0, stream>>>(E, Ebf, posArr, negArr);
    tl_gram<<<NPAIR, 256, 0, stream>>>(Ebf, labels, posArr, negArr);
    tl_final<<<1, 256, 0, stream>>>(posArr, negArr, out);
}